// Round 5
// baseline (102.714 us; speedup 1.0000x reference)
//
#include <hip/hip_runtime.h>
#include <hip/hip_bf16.h>
#include <stdint.h>

typedef __attribute__((ext_vector_type(8))) short short8;
typedef __attribute__((ext_vector_type(4))) short short4v;
typedef __attribute__((ext_vector_type(4))) float f32x4;

#define N_ROWS 8192
#define DIM 256            // K
#define BM 256             // i-rows per block (4 waves x 64 rows, a[4] frags)
#define BJ 128             // j-cols staged per LDS tile
#define JCHUNKS 16
#define JCHUNK (N_ROWS / JCHUNKS)   // 512 -> 4 tiles of 128 per block

// r' = r_normalized * sqrt(10*log2(e)); dot(r'_i,r'_j) = 10*log2(e)*sim,
// so exp(10*sim) = exp2(dot).
#define SCL 3.79828252f

__device__ __forceinline__ unsigned short f2bf(float f) {
  uint32_t u = __builtin_bit_cast(uint32_t, f);
  u += 0x7fffu + ((u >> 16) & 1u);  // RTNE
  return (unsigned short)(u >> 16);
}

// ---- Kernel A: normalize rows -> bf16 r'; zero den & out -------------------
__global__ void k_norm(const float* __restrict__ reps,
                       unsigned short* __restrict__ rq,
                       float* __restrict__ den,
                       float* __restrict__ out) {
  const int w = threadIdx.x >> 6, lane = threadIdx.x & 63;
  const int row = blockIdx.x * 4 + w;
  const float4 v = reinterpret_cast<const float4*>(reps + row * DIM)[lane];
  float ss = v.x * v.x + v.y * v.y + v.z * v.z + v.w * v.w;
#pragma unroll
  for (int m = 1; m < 64; m <<= 1) ss += __shfl_xor(ss, m);
  const float scale = SCL / fmaxf(sqrtf(ss), 1e-12f);
  short4v o;
  o.x = (short)f2bf(v.x * scale);
  o.y = (short)f2bf(v.y * scale);
  o.z = (short)f2bf(v.z * scale);
  o.w = (short)f2bf(v.w * scale);
  *reinterpret_cast<short4v*>(rq + row * DIM + lane * 4) = o;
  if (threadIdx.x < 4) den[blockIdx.x * 4 + threadIdx.x] = 0.0f;
  if (blockIdx.x == 0 && threadIdx.x == 0) out[0] = 0.0f;
}

// ---- Kernel B: fused sim + exp + mask + row-sum, 4x register blocking ------
// grid (32, 16): blockIdx.x = i-tile (256 rows), blockIdx.y = j-chunk (512).
// Each wave owns 64 i-rows (4 A-frag groups) so every B-fragment read from
// LDS feeds 4 MFMAs (was 2) -> LDS read traffic per output halves.
// waves_per_eu(2,2): pin EXACTLY 2 waves/SIMD (2 blocks/CU) so the backend
// budgets 256 VGPRs and keeps a[4][8] (128 VGPR) resident — with
// launch_bounds(256,2) it chased 4 waves/EU, capped at 128 VGPR, and
// rematerialized A from global inside the loop (R4: FETCH 78MB, 96us).
__global__ __attribute__((amdgpu_flat_work_group_size(256, 256),
                          amdgpu_waves_per_eu(2, 2))) void k_sim(
    const unsigned short* __restrict__ rq,
    const int* __restrict__ lab,
    float* __restrict__ den) {
  __shared__ unsigned short Bs[BJ * DIM];  // 64 KB, 16B-chunk XOR-swizzled

  const int tid = threadIdx.x;
  const int w = tid >> 6, lane = tid & 63;
  const int l15 = lane & 15, lq = lane >> 4;
  const int ibase = blockIdx.x * BM + w * 64;   // this wave's 64 rows
  const int jc0 = blockIdx.y * JCHUNK;

  // A fragments in registers: 4 i-subtiles x 8 k-chunks, 16B each (128 VGPR)
  short8 a[4][8];
#pragma unroll
  for (int t = 0; t < 4; ++t) {
    const unsigned short* ap = rq + (size_t)(ibase + t * 16 + l15) * DIM + lq * 8;
#pragma unroll
    for (int kc = 0; kc < 8; ++kc)
      a[t][kc] = *reinterpret_cast<const short8*>(ap + kc * 32);
  }
  // labels for the 16 output rows this lane owns (C/D: row=(lane>>4)*4+reg)
  int labi[4][4];
#pragma unroll
  for (int t = 0; t < 4; ++t)
#pragma unroll
    for (int r = 0; r < 4; ++r)
      labi[t][r] = lab[ibase + t * 16 + lq * 4 + r];

  f32x4 dsum[4] = {{0.f, 0.f, 0.f, 0.f}, {0.f, 0.f, 0.f, 0.f},
                   {0.f, 0.f, 0.f, 0.f}, {0.f, 0.f, 0.f, 0.f}};

  for (int jt = 0; jt < JCHUNK / BJ; ++jt) {
    const int j0 = jc0 + jt * BJ;
    __syncthreads();  // previous tile's reads done before overwrite
    // stage B tile: each wave stages 32 rows; LDS linear, global pre-swizzled
    {
      const int lrow0 = w * 32;
#pragma unroll
      for (int q = 0; q < 16; ++q) {
        const int lrow = lrow0 + q * 2 + (lane >> 5);
        const int ch = (lane & 31) ^ (lrow & 7);  // 16B-chunk swizzle
        const unsigned short* g = rq + (size_t)(j0 + lrow) * DIM + ch * 8;
        unsigned short* l = Bs + (lrow0 + q * 2) * DIM;  // +lane*16 implicit
        __builtin_amdgcn_global_load_lds(
            (const __attribute__((address_space(1))) uint32_t*)g,
            (__attribute__((address_space(3))) uint32_t*)l, 16, 0, 0);
      }
    }
    int labj[8];
#pragma unroll
    for (int s = 0; s < 8; ++s) labj[s] = lab[j0 + s * 16 + l15];

    __syncthreads();  // staging complete (compiler drains vmcnt(0))

#pragma unroll
    for (int s = 0; s < 8; ++s) {
      f32x4 acc[4] = {{0.f, 0.f, 0.f, 0.f}, {0.f, 0.f, 0.f, 0.f},
                      {0.f, 0.f, 0.f, 0.f}, {0.f, 0.f, 0.f, 0.f}};
      const int brow = s * 16 + l15;
      const unsigned short* bp = Bs + brow * DIM;
      const int sw = brow & 7;
#pragma unroll
      for (int kc = 0; kc < 8; ++kc) {
        const int c = (kc * 4 + lq) ^ sw;
        short8 bfr = *reinterpret_cast<const short8*>(bp + c * 8);
#pragma unroll
        for (int t = 0; t < 4; ++t)
          acc[t] = __builtin_amdgcn_mfma_f32_16x16x32_bf16(a[t][kc], bfr, acc[t], 0, 0, 0);
      }
#pragma unroll
      for (int t = 0; t < 4; ++t)
#pragma unroll
        for (int r = 0; r < 4; ++r) {
          float e = __builtin_amdgcn_exp2f(acc[t][r]);
          dsum[t][r] += (labi[t][r] == labj[s]) ? 1.0f : e;
        }
    }
  }

  // sum over the 16 lanes sharing each output row, then one atomic per row
#pragma unroll
  for (int t = 0; t < 4; ++t)
#pragma unroll
    for (int r = 0; r < 4; ++r) {
      float v = dsum[t][r];
      v += __shfl_xor(v, 1);
      v += __shfl_xor(v, 2);
      v += __shfl_xor(v, 4);
      v += __shfl_xor(v, 8);
      if (l15 == 0) atomicAdd(&den[ibase + t * 16 + lq * 4 + r], v);
    }
}

// ---- Kernel C: loss = mean(log(den + 1 + eps)) -----------------------------
__global__ void k_loss(const float* __restrict__ den, float* __restrict__ out) {
  const int idx = blockIdx.x * 256 + threadIdx.x;
  float v = logf(den[idx] + 1.0f + 1e-8f);  // +1 = num_diag
#pragma unroll
  for (int m = 1; m < 64; m <<= 1) v += __shfl_xor(v, m);
  __shared__ float sred[4];
  if ((threadIdx.x & 63) == 0) sred[threadIdx.x >> 6] = v;
  __syncthreads();
  if (threadIdx.x == 0)
    atomicAdd(out, (sred[0] + sred[1] + sred[2] + sred[3]) * (1.0f / (float)N_ROWS));
}

extern "C" void kernel_launch(void* const* d_in, const int* in_sizes, int n_in,
                              void* d_out, int out_size, void* d_ws, size_t ws_size,
                              hipStream_t stream) {
  const float* reps = (const float*)d_in[0];
  const int* lab = (const int*)d_in[1];
  float* out = (float*)d_out;
  unsigned short* rq = (unsigned short*)d_ws;                      // 4 MB bf16 r'
  float* den = (float*)((char*)d_ws + (size_t)N_ROWS * DIM * 2);   // 32 KB

  k_norm<<<N_ROWS / 4, 256, 0, stream>>>(reps, rq, den, out);
  k_sim<<<dim3(N_ROWS / BM, JCHUNKS), 256, 0, stream>>>(rq, lab, den);
  k_loss<<<N_ROWS / 256, 256, 0, stream>>>(den, out);
}

// Round 6
// 82.709 us; speedup vs baseline: 1.2419x; 1.2419x over previous
//
#include <hip/hip_runtime.h>
#include <hip/hip_bf16.h>
#include <stdint.h>

typedef __attribute__((ext_vector_type(8))) short short8;
typedef __attribute__((ext_vector_type(4))) short short4v;
typedef __attribute__((ext_vector_type(4))) float f32x4;

#define N_ROWS 8192
#define DIM 256            // K
#define BM 256             // i-rows per block (4 waves x 64 rows)
#define BJ 128             // j-cols staged per LDS tile
#define JCHUNKS 16
#define JCHUNK (N_ROWS / JCHUNKS)   // 512 -> 4 tiles of 128 per block

// r' = r_normalized * sqrt(10*log2(e)); dot(r'_i,r'_j) = 10*log2(e)*sim,
// so exp(10*sim) = exp2(dot).
#define SCL 3.79828252f

__device__ __forceinline__ unsigned short f2bf(float f) {
  uint32_t u = __builtin_bit_cast(uint32_t, f);
  u += 0x7fffu + ((u >> 16) & 1u);  // RTNE
  return (unsigned short)(u >> 16);
}

// ---- Kernel A: normalize rows -> bf16 r'; zero den & out -------------------
__global__ void k_norm(const float* __restrict__ reps,
                       unsigned short* __restrict__ rq,
                       float* __restrict__ den,
                       float* __restrict__ out) {
  const int w = threadIdx.x >> 6, lane = threadIdx.x & 63;
  const int row = blockIdx.x * 4 + w;
  const float4 v = reinterpret_cast<const float4*>(reps + row * DIM)[lane];
  float ss = v.x * v.x + v.y * v.y + v.z * v.z + v.w * v.w;
#pragma unroll
  for (int m = 1; m < 64; m <<= 1) ss += __shfl_xor(ss, m);
  const float scale = SCL / fmaxf(sqrtf(ss), 1e-12f);
  short4v o;
  o.x = (short)f2bf(v.x * scale);
  o.y = (short)f2bf(v.y * scale);
  o.z = (short)f2bf(v.z * scale);
  o.w = (short)f2bf(v.w * scale);
  *reinterpret_cast<short4v*>(rq + row * DIM + lane * 4) = o;
  if (threadIdx.x < 4) den[blockIdx.x * 4 + threadIdx.x] = 0.0f;
  if (blockIdx.x == 0 && threadIdx.x == 0) out[0] = 0.0f;
}

// ---- Kernel B: fused sim + exp + mask + row-sum, T=4, kc-outer -------------
// grid (32, 16). Each wave owns 64 i-rows; per B-fragment read from LDS we
// issue 4 MFMAs -> LDS bytes/FLOP is half of R1's. Loop nest is kc-OUTER so
// the persistent 128-float state is the MFMA accumulator acc[4][8] (AGPR
// file), while only 4 A-fragments (16 arch VGPRs) are live at a time,
// double-buffered from global (L1/L2-hot). This avoids the R4/R5 failure:
// a 128-VGPR arch-side A array spilled to scratch (FETCH 78MB, 96us).
__global__ __attribute__((amdgpu_flat_work_group_size(256, 256),
                          amdgpu_waves_per_eu(2, 2))) void k_sim(
    const unsigned short* __restrict__ rq,
    const int* __restrict__ lab,
    float* __restrict__ den) {
  __shared__ unsigned short Bs[BJ * DIM];  // 64 KB, 16B-chunk XOR-swizzled

  const int tid = threadIdx.x;
  const int w = tid >> 6, lane = tid & 63;
  const int l15 = lane & 15, lq = lane >> 4;
  const int ibase = blockIdx.x * BM + w * 64;   // this wave's 64 rows
  const int jc0 = blockIdx.y * JCHUNK;

  // A-row base pointers for the 4 i-subtiles (fragment: row=l15, k=lq*8..+8)
  const unsigned short* arow[4];
#pragma unroll
  for (int t = 0; t < 4; ++t)
    arow[t] = rq + (size_t)(ibase + t * 16 + l15) * DIM + lq * 8;

  int labi[4][4];
#pragma unroll
  for (int t = 0; t < 4; ++t)
#pragma unroll
    for (int r = 0; r < 4; ++r)
      labi[t][r] = lab[ibase + t * 16 + lq * 4 + r];

  f32x4 dsum[4] = {{0.f, 0.f, 0.f, 0.f}, {0.f, 0.f, 0.f, 0.f},
                   {0.f, 0.f, 0.f, 0.f}, {0.f, 0.f, 0.f, 0.f}};

  for (int jt = 0; jt < JCHUNK / BJ; ++jt) {
    const int j0 = jc0 + jt * BJ;
    __syncthreads();  // previous tile's reads done before overwrite
    // stage B tile: each wave stages 32 rows; LDS linear, global pre-swizzled
    {
      const int lrow0 = w * 32;
#pragma unroll
      for (int q = 0; q < 16; ++q) {
        const int lrow = lrow0 + q * 2 + (lane >> 5);
        const int ch = (lane & 31) ^ (lrow & 7);  // 16B-chunk swizzle
        const unsigned short* g = rq + (size_t)(j0 + lrow) * DIM + ch * 8;
        unsigned short* l = Bs + (lrow0 + q * 2) * DIM;  // +lane*16 implicit
        __builtin_amdgcn_global_load_lds(
            (const __attribute__((address_space(1))) uint32_t*)g,
            (__attribute__((address_space(3))) uint32_t*)l, 16, 0, 0);
      }
    }
    int labj[8];
#pragma unroll
    for (int s = 0; s < 8; ++s) labj[s] = lab[j0 + s * 16 + l15];

    // prefetch A fragments for kc=0 (overlaps with in-flight staging)
    short8 acur[4], anxt[4];
#pragma unroll
    for (int t = 0; t < 4; ++t)
      acur[t] = *reinterpret_cast<const short8*>(arow[t]);

    __syncthreads();  // staging complete (compiler drains vmcnt(0))

    // accumulators: 4 i-subtiles x 8 j-subtiles, persist across kc (AGPRs)
    f32x4 acc[4][8];
#pragma unroll
    for (int t = 0; t < 4; ++t)
#pragma unroll
      for (int s = 0; s < 8; ++s)
        acc[t][s] = (f32x4){0.f, 0.f, 0.f, 0.f};

#pragma unroll
    for (int kc = 0; kc < 8; ++kc) {
      // prefetch A for kc+1 while kc's 32 MFMAs execute
#pragma unroll
      for (int t = 0; t < 4; ++t)
        anxt[t] = (kc < 7)
            ? *reinterpret_cast<const short8*>(arow[t] + (kc + 1) * 32)
            : acur[t];
#pragma unroll
      for (int s = 0; s < 8; ++s) {
        const int brow = s * 16 + l15;
        const int c = (kc * 4 + lq) ^ (brow & 7);
        short8 bfr = *reinterpret_cast<const short8*>(Bs + brow * DIM + c * 8);
#pragma unroll
        for (int t = 0; t < 4; ++t)
          acc[t][s] =
              __builtin_amdgcn_mfma_f32_16x16x32_bf16(acur[t], bfr, acc[t][s], 0, 0, 0);
      }
#pragma unroll
      for (int t = 0; t < 4; ++t) acur[t] = anxt[t];
    }

    // epilogue: exp2 + label mask + row-sum accumulate
#pragma unroll
    for (int s = 0; s < 8; ++s)
#pragma unroll
      for (int t = 0; t < 4; ++t)
#pragma unroll
        for (int r = 0; r < 4; ++r) {
          float e = __builtin_amdgcn_exp2f(acc[t][s][r]);
          dsum[t][r] += (labi[t][r] == labj[s]) ? 1.0f : e;
        }
  }

  // sum over the 16 lanes sharing each output row, then one atomic per row
#pragma unroll
  for (int t = 0; t < 4; ++t)
#pragma unroll
    for (int r = 0; r < 4; ++r) {
      float v = dsum[t][r];
      v += __shfl_xor(v, 1);
      v += __shfl_xor(v, 2);
      v += __shfl_xor(v, 4);
      v += __shfl_xor(v, 8);
      if (l15 == 0) atomicAdd(&den[ibase + t * 16 + lq * 4 + r], v);
    }
}

// ---- Kernel C: loss = mean(log(den + 1 + eps)) -----------------------------
__global__ void k_loss(const float* __restrict__ den, float* __restrict__ out) {
  const int idx = blockIdx.x * 256 + threadIdx.x;
  float v = logf(den[idx] + 1.0f + 1e-8f);  // +1 = num_diag
#pragma unroll
  for (int m = 1; m < 64; m <<= 1) v += __shfl_xor(v, m);
  __shared__ float sred[4];
  if ((threadIdx.x & 63) == 0) sred[threadIdx.x >> 6] = v;
  __syncthreads();
  if (threadIdx.x == 0)
    atomicAdd(out, (sred[0] + sred[1] + sred[2] + sred[3]) * (1.0f / (float)N_ROWS));
}

extern "C" void kernel_launch(void* const* d_in, const int* in_sizes, int n_in,
                              void* d_out, int out_size, void* d_ws, size_t ws_size,
                              hipStream_t stream) {
  const float* reps = (const float*)d_in[0];
  const int* lab = (const int*)d_in[1];
  float* out = (float*)d_out;
  unsigned short* rq = (unsigned short*)d_ws;                      // 4 MB bf16 r'
  float* den = (float*)((char*)d_ws + (size_t)N_ROWS * DIM * 2);   // 32 KB

  k_norm<<<N_ROWS / 4, 256, 0, stream>>>(reps, rq, den, out);
  k_sim<<<dim3(N_ROWS / BM, JCHUNKS), 256, 0, stream>>>(rq, lab, den);
  k_loss<<<N_ROWS / 256, 256, 0, stream>>>(den, out);
}

// Round 7
// 48.577 us; speedup vs baseline: 2.1144x; 1.7026x over previous
//
#include <hip/hip_runtime.h>
#include <hip/hip_bf16.h>
#include <stdint.h>

typedef __attribute__((ext_vector_type(8))) short short8;
typedef __attribute__((ext_vector_type(4))) short short4v;
typedef __attribute__((ext_vector_type(4))) float f32x4;

#define N_ROWS 8192
#define DIM 256            // K
#define BM 256             // i-rows per block (8 waves x 32 rows, t=2)
#define BJ 128             // j-cols staged per LDS tile
#define JCHUNKS 8
#define JCHUNK (N_ROWS / JCHUNKS)   // 1024 -> 8 tiles of 128 per block

// r' = r_normalized * sqrt(10*log2(e)); dot(r'_i,r'_j) = 10*log2(e)*sim,
// so exp(10*sim) = exp2(dot).
#define SCL 3.79828252f

__device__ __forceinline__ unsigned short f2bf(float f) {
  uint32_t u = __builtin_bit_cast(uint32_t, f);
  u += 0x7fffu + ((u >> 16) & 1u);  // RTNE
  return (unsigned short)(u >> 16);
}

// ---- Kernel A: normalize rows -> bf16 r'; zero den & out -------------------
__global__ void k_norm(const float* __restrict__ reps,
                       unsigned short* __restrict__ rq,
                       float* __restrict__ den,
                       float* __restrict__ out) {
  const int w = threadIdx.x >> 6, lane = threadIdx.x & 63;
  const int row = blockIdx.x * 4 + w;
  const float4 v = reinterpret_cast<const float4*>(reps + row * DIM)[lane];
  float ss = v.x * v.x + v.y * v.y + v.z * v.z + v.w * v.w;
#pragma unroll
  for (int m = 1; m < 64; m <<= 1) ss += __shfl_xor(ss, m);
  const float scale = SCL / fmaxf(sqrtf(ss), 1e-12f);
  short4v o;
  o.x = (short)f2bf(v.x * scale);
  o.y = (short)f2bf(v.y * scale);
  o.z = (short)f2bf(v.z * scale);
  o.w = (short)f2bf(v.w * scale);
  *reinterpret_cast<short4v*>(rq + row * DIM + lane * 4) = o;
  if (threadIdx.x < 4) den[blockIdx.x * 4 + threadIdx.x] = 0.0f;
  if (blockIdx.x == 0 && threadIdx.x == 0) out[0] = 0.0f;
}

// ---- Kernel B: fused sim + exp + mask + row-sum, double-buffered LDS -------
// grid (32, 8), 512 threads (8 waves), 1 block/CU. R1's proven no-spill
// register layout (t=2, a[2][8] = 64 VGPR). Two 64KB LDS buffers; per tile:
//   barrier -> issue stage(next tile -> other buf) -> compute current buf.
// The vmcnt(0) drain at each barrier waits on loads issued a full compute
// phase earlier, so staging latency is hidden (R1 exposed it every tile).
__global__ __launch_bounds__(512, 2) void k_sim(
    const unsigned short* __restrict__ rq,
    const int* __restrict__ lab,
    float* __restrict__ den) {
  __shared__ unsigned short Bs[2 * BJ * DIM];  // 128 KB, 16B-chunk XOR-swizzled

  const int tid = threadIdx.x;
  const int w = tid >> 6, lane = tid & 63;
  const int l15 = lane & 15, lq = lane >> 4;
  const int ibase = blockIdx.x * BM + w * 32;   // this wave's 32 rows
  const int jc0 = blockIdx.y * JCHUNK;

  // A fragments in registers: 2 i-subtiles x 8 k-chunks (64 VGPR, no spill)
  short8 a[2][8];
#pragma unroll
  for (int t = 0; t < 2; ++t) {
    const unsigned short* ap = rq + (size_t)(ibase + t * 16 + l15) * DIM + lq * 8;
#pragma unroll
    for (int kc = 0; kc < 8; ++kc)
      a[t][kc] = *reinterpret_cast<const short8*>(ap + kc * 32);
  }
  int labi[2][4];
#pragma unroll
  for (int t = 0; t < 2; ++t)
#pragma unroll
    for (int r = 0; r < 4; ++r)
      labi[t][r] = lab[ibase + t * 16 + lq * 4 + r];

  f32x4 dsum[2] = {{0.f, 0.f, 0.f, 0.f}, {0.f, 0.f, 0.f, 0.f}};

  // stage helper pattern: each wave stages 16 rows of the 128-row tile
  const int lrow0 = w * 16;

  // prologue: stage tile 0 into buf 0
  {
    const int j0 = jc0;
#pragma unroll
    for (int q = 0; q < 8; ++q) {
      const int lrow = lrow0 + q * 2 + (lane >> 5);
      const int ch = (lane & 31) ^ (lrow & 7);  // 16B-chunk swizzle
      const unsigned short* g = rq + (size_t)(j0 + lrow) * DIM + ch * 8;
      unsigned short* l = Bs + (lrow0 + q * 2) * DIM;  // +lane*16 implicit
      __builtin_amdgcn_global_load_lds(
          (const __attribute__((address_space(1))) uint32_t*)g,
          (__attribute__((address_space(3))) uint32_t*)l, 16, 0, 0);
    }
  }

  for (int jt = 0; jt < JCHUNK / BJ; ++jt) {
    const int cur = jt & 1;
    const int j0 = jc0 + jt * BJ;

    __syncthreads();  // buf[cur] staged (vmcnt drained); prev reads of buf[cur^1] done

    // issue staging of NEXT tile into the other buffer (hidden under compute)
    if (jt < JCHUNK / BJ - 1) {
      const int jn = j0 + BJ;
#pragma unroll
      for (int q = 0; q < 8; ++q) {
        const int lrow = lrow0 + q * 2 + (lane >> 5);
        const int ch = (lane & 31) ^ (lrow & 7);
        const unsigned short* g = rq + (size_t)(jn + lrow) * DIM + ch * 8;
        unsigned short* l = Bs + ((cur ^ 1) * BJ + lrow0 + q * 2) * DIM;
        __builtin_amdgcn_global_load_lds(
            (const __attribute__((address_space(1))) uint32_t*)g,
            (__attribute__((address_space(3))) uint32_t*)l, 16, 0, 0);
      }
    }

    int labj[8];
#pragma unroll
    for (int s = 0; s < 8; ++s) labj[s] = lab[j0 + s * 16 + l15];

    const unsigned short* Bb = Bs + cur * BJ * DIM;
#pragma unroll
    for (int s = 0; s < 8; ++s) {
      f32x4 acc0 = {0.f, 0.f, 0.f, 0.f};
      f32x4 acc1 = {0.f, 0.f, 0.f, 0.f};
      const int brow = s * 16 + l15;
      const unsigned short* bp = Bb + brow * DIM;
      const int sw = brow & 7;
#pragma unroll
      for (int kc = 0; kc < 8; ++kc) {
        const int c = (kc * 4 + lq) ^ sw;
        short8 bfr = *reinterpret_cast<const short8*>(bp + c * 8);
        acc0 = __builtin_amdgcn_mfma_f32_16x16x32_bf16(a[0][kc], bfr, acc0, 0, 0, 0);
        acc1 = __builtin_amdgcn_mfma_f32_16x16x32_bf16(a[1][kc], bfr, acc1, 0, 0, 0);
      }
#pragma unroll
      for (int r = 0; r < 4; ++r) {
        float e0 = __builtin_amdgcn_exp2f(acc0[r]);
        float e1 = __builtin_amdgcn_exp2f(acc1[r]);
        dsum[0][r] += (labi[0][r] == labj[s]) ? 1.0f : e0;
        dsum[1][r] += (labi[1][r] == labj[s]) ? 1.0f : e1;
      }
    }
  }

  // sum over the 16 lanes sharing each output row, then one atomic per row
#pragma unroll
  for (int t = 0; t < 2; ++t)
#pragma unroll
    for (int r = 0; r < 4; ++r) {
      float v = dsum[t][r];
      v += __shfl_xor(v, 1);
      v += __shfl_xor(v, 2);
      v += __shfl_xor(v, 4);
      v += __shfl_xor(v, 8);
      if (l15 == 0) atomicAdd(&den[ibase + t * 16 + lq * 4 + r], v);
    }
}

// ---- Kernel C: loss = mean(log(den + 1 + eps)) -----------------------------
__global__ void k_loss(const float* __restrict__ den, float* __restrict__ out) {
  const int idx = blockIdx.x * 256 + threadIdx.x;
  float v = logf(den[idx] + 1.0f + 1e-8f);  // +1 = num_diag
#pragma unroll
  for (int m = 1; m < 64; m <<= 1) v += __shfl_xor(v, m);
  __shared__ float sred[4];
  if ((threadIdx.x & 63) == 0) sred[threadIdx.x >> 6] = v;
  __syncthreads();
  if (threadIdx.x == 0)
    atomicAdd(out, (sred[0] + sred[1] + sred[2] + sred[3]) * (1.0f / (float)N_ROWS));
}

extern "C" void kernel_launch(void* const* d_in, const int* in_sizes, int n_in,
                              void* d_out, int out_size, void* d_ws, size_t ws_size,
                              hipStream_t stream) {
  const float* reps = (const float*)d_in[0];
  const int* lab = (const int*)d_in[1];
  float* out = (float*)d_out;
  unsigned short* rq = (unsigned short*)d_ws;                      // 4 MB bf16 r'
  float* den = (float*)((char*)d_ws + (size_t)N_ROWS * DIM * 2);   // 32 KB

  k_norm<<<N_ROWS / 4, 256, 0, stream>>>(reps, rq, den, out);
  k_sim<<<dim3(N_ROWS / BM, JCHUNKS), 512, 0, stream>>>(rq, lab, den);
  k_loss<<<N_ROWS / 256, 256, 0, stream>>>(den, out);
}

// Round 8
// 41.060 us; speedup vs baseline: 2.5016x; 1.1831x over previous
//
#include <hip/hip_runtime.h>
#include <hip/hip_bf16.h>
#include <hip/hip_fp8.h>
#include <stdint.h>

typedef __attribute__((ext_vector_type(4))) float f32x4;
typedef __attribute__((ext_vector_type(2))) unsigned int u32x2;
typedef __attribute__((ext_vector_type(4))) unsigned int u32x4;

#define N_ROWS 8192
#define DIM 256            // K (bytes per row in fp8)
#define BM 128             // i-rows per block (4 waves x 32 rows, t=2)
#define BJ 128             // j-cols staged per LDS tile
#define JCHUNKS 8
#define JCHUNK (N_ROWS / JCHUNKS)   // 1024 -> 8 tiles of 128 per block

// r' = r_normalized * sqrt(10*log2(e)); dot(r'_i,r'_j) = 10*log2(e)*sim,
// so exp(10*sim) = exp2(dot).
#define SCL 3.79828252f

// ---- Kernel A: normalize rows -> fp8 e4m3 r'; zero den & out ---------------
__global__ void k_norm(const float* __restrict__ reps,
                       unsigned char* __restrict__ rq,
                       float* __restrict__ den,
                       float* __restrict__ out) {
  const int w = threadIdx.x >> 6, lane = threadIdx.x & 63;
  const int row = blockIdx.x * 4 + w;
  const float4 v = reinterpret_cast<const float4*>(reps + row * DIM)[lane];
  float ss = v.x * v.x + v.y * v.y + v.z * v.z + v.w * v.w;
#pragma unroll
  for (int m = 1; m < 64; m <<= 1) ss += __shfl_xor(ss, m);
  const float scale = SCL / fmaxf(sqrtf(ss), 1e-12f);
  // OCP e4m3 (gfx950 native); |r'| <= 3.8 << 448, no saturation concerns
  const uint32_t b0 = __hip_fp8_e4m3(v.x * scale).__x;
  const uint32_t b1 = __hip_fp8_e4m3(v.y * scale).__x;
  const uint32_t b2 = __hip_fp8_e4m3(v.z * scale).__x;
  const uint32_t b3 = __hip_fp8_e4m3(v.w * scale).__x;
  *reinterpret_cast<uint32_t*>(rq + (size_t)row * DIM + lane * 4) =
      b0 | (b1 << 8) | (b2 << 16) | (b3 << 24);
  if (threadIdx.x < 4) den[blockIdx.x * 4 + threadIdx.x] = 0.0f;
  if (blockIdx.x == 0 && threadIdx.x == 0) out[0] = 0.0f;
}

// ---- Kernel B: fp8 fused sim + exp + mask + row-sum, dbuf LDS --------------
// grid (64, 8), 256 threads (4 waves), 2 blocks/CU (2 x 64KB LDS).
// fp8 halves LDS bytes/FLOP vs bf16: each ds_read_b128 (one kc-pair) feeds
// 4 MFMAs (16x16x32 fp8 = bf16 rate). A stays in registers (32 VGPR).
// Double-buffered: barrier -> stage(next -> other buf) -> compute current.
__global__ __launch_bounds__(256, 2) void k_sim(
    const unsigned char* __restrict__ rq,
    const int* __restrict__ lab,
    float* __restrict__ den) {
  __shared__ unsigned char Bs[2][BJ * DIM];  // 2 x 32 KB, 16B-chunk XOR-swizzled

  const int tid = threadIdx.x;
  const int w = tid >> 6, lane = tid & 63;
  const int l15 = lane & 15, lq = lane >> 4;
  const int ibase = blockIdx.x * BM + w * 32;   // this wave's 32 rows
  const int jc0 = blockIdx.y * JCHUNK;

  // A fragments: 2 i-subtiles x 8 k-chunks (8B each) = 32 VGPR.
  // Fragment convention (same for A and B so any k-permutation cancels):
  // MFMA (kc2,half) consumes row bytes [kc2*64 + lq*16 + half*8, +8).
  long a[2][8];
#pragma unroll
  for (int t = 0; t < 2; ++t) {
    const unsigned char* ap =
        rq + (size_t)(ibase + t * 16 + l15) * DIM + lq * 16;
#pragma unroll
    for (int kc2 = 0; kc2 < 4; ++kc2) {
      const u32x4 v = *reinterpret_cast<const u32x4*>(ap + kc2 * 64);
      a[t][2 * kc2]     = __builtin_bit_cast(long, (u32x2){v.x, v.y});
      a[t][2 * kc2 + 1] = __builtin_bit_cast(long, (u32x2){v.z, v.w});
    }
  }
  int labi[2][4];
#pragma unroll
  for (int t = 0; t < 2; ++t)
#pragma unroll
    for (int r = 0; r < 4; ++r)
      labi[t][r] = lab[ibase + t * 16 + lq * 4 + r];

  f32x4 dsum[2] = {{0.f, 0.f, 0.f, 0.f}, {0.f, 0.f, 0.f, 0.f}};

  const int lrow0 = w * 32;  // each wave stages 32 rows (8 instr x 4 rows)

  // prologue: stage tile 0 into buf 0
#pragma unroll
  for (int q = 0; q < 8; ++q) {
    const int lrow = lrow0 + q * 4 + lq;
    const int ch = l15 ^ (lrow & 7);  // 16B-chunk swizzle
    const unsigned char* g = rq + (size_t)(jc0 + lrow) * DIM + ch * 16;
    unsigned char* l = Bs[0] + (lrow0 + q * 4) * DIM;  // +lane*16 implicit
    __builtin_amdgcn_global_load_lds(
        (const __attribute__((address_space(1))) uint32_t*)g,
        (__attribute__((address_space(3))) uint32_t*)l, 16, 0, 0);
  }

  for (int jt = 0; jt < JCHUNK / BJ; ++jt) {
    const int cur = jt & 1;
    const int j0 = jc0 + jt * BJ;

    __syncthreads();  // buf[cur] staged; prior reads of buf[cur^1] done

    // issue staging of NEXT tile into the other buffer (hidden under compute)
    if (jt < JCHUNK / BJ - 1) {
      const int jn = j0 + BJ;
#pragma unroll
      for (int q = 0; q < 8; ++q) {
        const int lrow = lrow0 + q * 4 + lq;
        const int ch = l15 ^ (lrow & 7);
        const unsigned char* g = rq + (size_t)(jn + lrow) * DIM + ch * 16;
        unsigned char* l = Bs[cur ^ 1] + (lrow0 + q * 4) * DIM;
        __builtin_amdgcn_global_load_lds(
            (const __attribute__((address_space(1))) uint32_t*)g,
            (__attribute__((address_space(3))) uint32_t*)l, 16, 0, 0);
      }
    }

    int labj[8];
#pragma unroll
    for (int s = 0; s < 8; ++s) labj[s] = lab[j0 + s * 16 + l15];

    const unsigned char* Bb = Bs[cur];
#pragma unroll
    for (int s = 0; s < 8; ++s) {
      f32x4 acc0 = {0.f, 0.f, 0.f, 0.f};
      f32x4 acc1 = {0.f, 0.f, 0.f, 0.f};
      const int brow = s * 16 + l15;
      const unsigned char* bp = Bb + brow * DIM;
      const int sw = brow & 7;
#pragma unroll
      for (int kc2 = 0; kc2 < 4; ++kc2) {
        const int ch = (kc2 * 4 + lq) ^ sw;
        const u32x4 bv = *reinterpret_cast<const u32x4*>(bp + ch * 16);
        const long blo = __builtin_bit_cast(long, (u32x2){bv.x, bv.y});
        const long bhi = __builtin_bit_cast(long, (u32x2){bv.z, bv.w});
        acc0 = __builtin_amdgcn_mfma_f32_16x16x32_fp8_fp8(a[0][2 * kc2], blo, acc0, 0, 0, 0);
        acc1 = __builtin_amdgcn_mfma_f32_16x16x32_fp8_fp8(a[1][2 * kc2], blo, acc1, 0, 0, 0);
        acc0 = __builtin_amdgcn_mfma_f32_16x16x32_fp8_fp8(a[0][2 * kc2 + 1], bhi, acc0, 0, 0, 0);
        acc1 = __builtin_amdgcn_mfma_f32_16x16x32_fp8_fp8(a[1][2 * kc2 + 1], bhi, acc1, 0, 0, 0);
      }
#pragma unroll
      for (int r = 0; r < 4; ++r) {
        float e0 = __builtin_amdgcn_exp2f(acc0[r]);
        float e1 = __builtin_amdgcn_exp2f(acc1[r]);
        dsum[0][r] += (labi[0][r] == labj[s]) ? 1.0f : e0;
        dsum[1][r] += (labi[1][r] == labj[s]) ? 1.0f : e1;
      }
    }
  }

  // sum over the 16 lanes sharing each output row, then one atomic per row
#pragma unroll
  for (int t = 0; t < 2; ++t)
#pragma unroll
    for (int r = 0; r < 4; ++r) {
      float v = dsum[t][r];
      v += __shfl_xor(v, 1);
      v += __shfl_xor(v, 2);
      v += __shfl_xor(v, 4);
      v += __shfl_xor(v, 8);
      if (l15 == 0) atomicAdd(&den[ibase + t * 16 + lq * 4 + r], v);
    }
}

// ---- Kernel C: loss = mean(log(den + 1 + eps)) -----------------------------
__global__ void k_loss(const float* __restrict__ den, float* __restrict__ out) {
  const int idx = blockIdx.x * 256 + threadIdx.x;
  float v = logf(den[idx] + 1.0f + 1e-8f);  // +1 = num_diag
#pragma unroll
  for (int m = 1; m < 64; m <<= 1) v += __shfl_xor(v, m);
  __shared__ float sred[4];
  if ((threadIdx.x & 63) == 0) sred[threadIdx.x >> 6] = v;
  __syncthreads();
  if (threadIdx.x == 0)
    atomicAdd(out, (sred[0] + sred[1] + sred[2] + sred[3]) * (1.0f / (float)N_ROWS));
}

extern "C" void kernel_launch(void* const* d_in, const int* in_sizes, int n_in,
                              void* d_out, int out_size, void* d_ws, size_t ws_size,
                              hipStream_t stream) {
  const float* reps = (const float*)d_in[0];
  const int* lab = (const int*)d_in[1];
  float* out = (float*)d_out;
  unsigned char* rq = (unsigned char*)d_ws;                        // 2 MB fp8 r'
  float* den = (float*)((char*)d_ws + (size_t)N_ROWS * DIM);       // 32 KB

  k_norm<<<N_ROWS / 4, 256, 0, stream>>>(reps, rq, den, out);
  k_sim<<<dim3(N_ROWS / BM, JCHUNKS), 256, 0, stream>>>(rq, lab, den);
  k_loss<<<N_ROWS / 256, 256, 0, stream>>>(den, out);
}